// Round 20
// baseline (173.198 us; speedup 1.0000x reference)
//
#include <hip/hip_runtime.h>
#include <hip/hip_bf16.h>
#include <stdint.h>

#define HH 96
#define WW 96
#define NCH 256
#define PH 95
#define PW 95
#define NP 9025          // PH*PW
#define DD 1024          // 4*NCH (bytes per row in i8)
#define FEPS 1e-8f

#define BMT 128          // target rows per block
#define BNS 256          // source cols per block
#define NTM 72           // row tiles (9216/128)
#define NTN 36           // col tiles (9216/256)
#define NPAD2 9216
#define NBLK3 2592       // NTM*NTN (divisible by 8)
#define KT 16            // DD/64
#define QSCL 508.0f
#define QS2 (1.0f / (508.0f * 508.0f))
#define DBIAS (1 << 19)  // dot bias (Cauchy-Schwarz: |dot| <= ~274K < 2^19)

typedef __attribute__((ext_vector_type(4))) int i32x4;
typedef __attribute__((ext_vector_type(4))) unsigned int u32x4;
typedef unsigned long long u64;
typedef unsigned int u32;
using bf16 = __hip_bfloat16;

__device__ __forceinline__ u32 umx(u32 a, u32 b) { return a > b ? a : b; }
__device__ __forceinline__ u64 umax(u64 a, u64 b) { return a > b ? a : b; }

// per-pixel partial (64-ch) sum of squares; g=blockIdx.y, img=blockIdx.z.
// Also zeroes pad rows of Sq/Tq (g==0), rowP/colP (g==1), and the counter.
__global__ __launch_bounds__(256) void k_q(const float* __restrict__ src,
                                           const float* __restrict__ tgt,
                                           float* __restrict__ qpart,
                                           int8_t* __restrict__ Sq,
                                           int8_t* __restrict__ Tq,
                                           u64* __restrict__ rowP,
                                           u64* __restrict__ colP,
                                           u32* __restrict__ ctr) {
  int p = blockIdx.x * 256 + threadIdx.x;  // 36*256 == 9216 exactly
  int g = blockIdx.y;                      // channel group (4 x 64)
  const float* img = blockIdx.z ? tgt : src;
  const float* base = img + (size_t)(g * 64) * (HH * WW);
  float acc = 0.f;
  #pragma unroll 8
  for (int c = 0; c < 64; ++c) {
    float v = base[(size_t)c * (HH * WW) + p];
    acc = fmaf(v, v, acc);
  }
  qpart[((size_t)blockIdx.z * 4 + g) * (HH * WW) + p] = acc;
  if (g == 0) {  // zero pad rows NP..NPAD2 (pad dot = 0, never wins)
    const int padWords = (NPAD2 - NP) * DD / 4;  // u32 words
    u32* pw = (u32*)((blockIdx.z ? Tq : Sq) + (size_t)NP * DD);
    for (int j = p; j < padWords; j += 36 * 256) pw[j] = 0u;
  }
  if (g == 1) {  // zero the argmax accumulators (atomicMax targets)
    (blockIdx.z ? colP : rowP)[p] = 0ull;
  }
  if (p == 0 && g == 0 && blockIdx.z == 0) *ctr = 0u;
}

// normalized, globally-scaled i8 patch matrix [NPAD2][DD] via LDS transpose.
// jx-FOLDED (R19): one block loads a full 96-col image row once and emits
// BOTH column shifts -> image reads halved. Per-row sq recomputed in-block
// from qpart; bx==0 blocks store sq. 16 i8 -> one dwordx4 store.
// grid (8 = iy*4+cgroup, PH, z); z = 0: src -> Sq, sq_s ; z = 1: tgt -> Tq.
__global__ __launch_bounds__(128) void k_norm(const float* __restrict__ src,
                                              const float* __restrict__ tgt,
                                              const float* __restrict__ qpart,
                                              float* __restrict__ sq_s,
                                              float* __restrict__ sq_t,
                                              int8_t* __restrict__ Sq,
                                              int8_t* __restrict__ Tq) {
  __shared__ float tile[64 * 97];   // [c][x], odd stride
  __shared__ float rn[PW];
  const float* img = blockIdx.z ? tgt : src;
  int8_t* out = blockIdx.z ? Tq : Sq;
  int bx = blockIdx.x;
  int iy = bx >> 2;                 // row shift
  int c0 = (bx & 3) * 64;           // channel group
  int y = blockIdx.y;
  int t = threadIdx.x;
  if (t < PW) {                     // recompute per-patch squared norm locally
    const float* qp = qpart + (size_t)blockIdx.z * 4 * (HH * WW);
    int b = y * WW + t;
    float s = 0.f;
    #pragma unroll
    for (int g = 0; g < 4; ++g) {
      const float* q = qp + (size_t)g * (HH * WW);
      s += q[b] + q[b + 1] + q[b + WW] + q[b + WW + 1];
    }
    if (bx == 0) (blockIdx.z ? sq_t : sq_s)[y * PW + t] = s;
    rn[t] = QSCL / (sqrtf(s) + FEPS);
  }
  if (t < 96) {                     // load 64 channels x full 96-col row y+iy
    const float* base = img + (size_t)(y + iy) * WW + t;
    #pragma unroll 4
    for (int c = 0; c < 64; ++c)
      tile[c * 97 + t] = base[(size_t)(c0 + c) * (HH * WW)];
  }
  __syncthreads();
  int part = t & 3;                 // 16 d's per part
  int xl0 = t >> 2;                 // 32 xl per pass
  #pragma unroll
  for (int jx = 0; jx < 2; ++jx) {
    int d0 = (iy * 2 + jx) * 256 + c0 + part * 16;
    #pragma unroll
    for (int pass = 0; pass < 3; ++pass) {
      int xl = xl0 + pass * 32;
      if (xl < PW) {
        float r = rn[xl];
        u32x4 w;
        #pragma unroll
        for (int g = 0; g < 4; ++g) {
          u32 pk = 0;
          #pragma unroll
          for (int bb = 0; bb < 4; ++bb) {
            int dl = part * 16 + g * 4 + bb;
            float qv = tile[dl * 97 + xl + jx] * r;
            qv = fminf(fmaxf(qv, -127.f), 127.f);
            pk |= ((u32)(uint8_t)(int8_t)(int)rintf(qv)) << (8 * bb);
          }
          w[g] = pk;
        }
        *(u32x4*)(out + (size_t)(y * PW + xl) * DD + d0) = w;
      }
    }
  }
}

// ---- inline-asm helpers ----
#define DSR(dst, base, IMMSTR) \
  asm volatile("ds_read_b128 %0, %1 offset:" IMMSTR : "=v"(dst) : "v"(base))
#define WAITL(NSTR) asm volatile("s_waitcnt lgkmcnt(" NSTR ")" ::: "memory")
#define WAITV(NSTR) asm volatile("s_waitcnt vmcnt(" NSTR ")" ::: "memory")
#define SB0 __builtin_amdgcn_sched_barrier(0)

// 128x256-tile i8 MFMA GEMM (dot = Tq . Sq^T exact i32; cos = dot*QS2).
// R20: ONE barrier per K-tile. 3-buffer ring, distance-2 prefetch; per tile:
//   vmcnt(3) [own tile-t loads retired, pre-covered by 2 tiles of compute]
//   s_barrier [joint guarantee: ALL waves' t-loads landed (each vmcnt'd
//              before the barrier) AND all waves done reading tile t-1]
//   STAGE(t+2 -> buf (t+2)%3 == (t-1)%3, just freed)   [WAR safe]
//   KSRUN(t)                                           [RAW safe]
// Halves barrier count vs R11/R14 (32 -> 16). R17 L2-aware tile order +
// R18 atomicMax epilogue. LDS: 3 x 24 KiB = 72 KiB; 2 blocks/CU.
// NOTE: 128 regs/wave (64 VGPR + 64 acc) x 16 waves/CU = full register pool;
// (512,6) spills catastrophically (R12).
__global__ __launch_bounds__(512, 4) void k_gemm(const int8_t* __restrict__ Tq,
                                                 const int8_t* __restrict__ Sq,
                                                 u64* __restrict__ rowP,
                                                 u64* __restrict__ colP) {
  __shared__ __align__(16) char ldsc[73728];   // 3 x 24 KiB

  int bid = blockIdx.x;
  // L2-aware order: XCD = bid&7 owns rt in [xcd*9, xcd*9+9); within the XCD,
  // 3 ct-stripes of 12, rt-major inside each stripe. Bijective: 8*3*9*12=2592.
  int xcd = bid & 7, loc = bid >> 3;     // loc in [0, 324)
  int stripe = loc / 108;                // 0..2
  int w2 = loc - stripe * 108;           // 0..107
  int rt = xcd * 9 + w2 / 12;
  int ct = stripe * 12 + (w2 % 12);
  int tileR = rt * BMT, tileC = ct * BNS;

  int tid = threadIdx.x;
  int lane = tid & 63, wid = tid >> 6;
  int wm = wid >> 2, wn = wid & 3;       // 2 x 4 wave grid; per-wave out 64x64
  int lcol = lane & 15, lrow = lane >> 4;

  const int8_t* gA = Tq + (size_t)tileR * DD;
  const int8_t* gB = Sq + (size_t)tileC * DD;

  i32x4 acc[4][4] = {};

  // LDS read bases: swizzle term (lrow ^ ((lcol>>1)&3))*16, fragment-invariant
  u32 lbase = (u32)(uintptr_t)ldsc;
  u32 swz16 = ((u32)(lrow ^ ((lcol >> 1) & 3))) << 4;
  u32 aoff0 = lbase + (u32)(wm * 64 + lcol) * 64u + swz16;
  u32 boff0 = lbase + 8192u + (u32)(wn * 64 + lcol) * 64u + swz16;
  u32 aoff1 = aoff0 + 24576u, boff1 = boff0 + 24576u;
  u32 aoff2 = aoff0 + 49152u, boff2 = boff0 + 49152u;

  // stage K-tile t into ring buf db: linear LDS dest + inverse-swizzled col
  auto STAGE = [&](int db, int t) {
    int k0 = t * 64;
    {
      int r = tid >> 2, s = tid & 3;     // A: 128x64B, 1 chunk/thread
      const int8_t* g = gA + (size_t)r * DD + k0 + ((s ^ ((r >> 1) & 3)) << 4);
      __builtin_amdgcn_global_load_lds(
          (const __attribute__((address_space(1))) void*)g,
          (__attribute__((address_space(3))) void*)(ldsc + db * 24576 + tid * 16),
          16, 0, 0);
    }
    #pragma unroll
    for (int q2 = 0; q2 < 2; ++q2) {     // B: 256x64B, 2 chunks/thread
      int ch = q2 * 512 + tid;
      int r = ch >> 2, s = ch & 3;
      const int8_t* g = gB + (size_t)r * DD + k0 + ((s ^ ((r >> 1) & 3)) << 4);
      __builtin_amdgcn_global_load_lds(
          (const __attribute__((address_space(1))) void*)g,
          (__attribute__((address_space(3))) void*)(ldsc + db * 24576 + 8192 + ch * 16),
          16, 0, 0);
    }
  };

  i32x4 a[4], b[4];
#define MM(m) do { \
    acc[m][0] = __builtin_amdgcn_mfma_i32_16x16x64_i8(a[m], b[0], acc[m][0], 0, 0, 0); \
    acc[m][1] = __builtin_amdgcn_mfma_i32_16x16x64_i8(a[m], b[1], acc[m][1], 0, 0, 0); \
    acc[m][2] = __builtin_amdgcn_mfma_i32_16x16x64_i8(a[m], b[2], acc[m][2], 0, 0, 0); \
    acc[m][3] = __builtin_amdgcn_mfma_i32_16x16x64_i8(a[m], b[3], acc[m][3], 0, 0, 0); \
  } while (0)

#define KSRUN(AOFF, BOFF) do { \
    DSR(a[0], AOFF, "0"); \
    DSR(b[0], BOFF, "0");    DSR(b[1], BOFF, "1024"); \
    DSR(b[2], BOFF, "2048"); DSR(b[3], BOFF, "3072"); \
    DSR(a[1], AOFF, "1024"); DSR(a[2], AOFF, "2048"); DSR(a[3], AOFF, "3072"); \
    __builtin_amdgcn_s_setprio(1); \
    WAITL("3"); SB0; MM(0); \
    WAITL("2"); SB0; MM(1); \
    WAITL("1"); SB0; MM(2); \
    WAITL("0"); SB0; MM(3); \
    __builtin_amdgcn_s_setprio(0); \
  } while (0)

  // prologue: prime distance-2 ring
  STAGE(0, 0);
  STAGE(1, 1);
  // 16 tiles = 5 groups of 3 + tail tile 15 (buf 0). One barrier per tile.
  #pragma unroll 1
  for (int i = 0; i < 5; ++i) {
    int t0 = 3 * i;
    // tile t0 (buf 0): stage t0+2 -> buf 2
    WAITV("3"); __builtin_amdgcn_s_barrier();
    STAGE(2, t0 + 2);
    KSRUN(aoff0, boff0);
    // tile t0+1 (buf 1): stage t0+3 -> buf 0
    WAITV("3"); __builtin_amdgcn_s_barrier();
    STAGE(0, t0 + 3);
    KSRUN(aoff1, boff1);
    // tile t0+2 (buf 2): stage t0+4 -> buf 1 (skip when t0+4 == 16)
    WAITV("3"); __builtin_amdgcn_s_barrier();
    if (i < 4) STAGE(1, t0 + 4);
    KSRUN(aoff2, boff2);
  }
  // tile 15 (buf 0)
  WAITV("0"); __builtin_amdgcn_s_barrier();
  KSRUN(aoff0, boff0);

  // ---- epilogue: integer-key argmax -> LDS block-reduce -> atomicMax ----
  __syncthreads();                  // full drain; LDS now reusable
  u64* rowLds = (u64*)ldsc;           // [4 wn][128 rows]  4KB
  u64* colLds = (u64*)(ldsc + 4096);  // [2 wm][256 cols]  4KB

  const u32 KB = ((u32)DBIAS) << 8;   // bias<<8
  // row best: per target row (m,lrow,j), reduce over n then lcol (16 lanes)
  u32 Cr0 = KB + 255u - (u32)(wn * 64 + lcol);
  #pragma unroll
  for (int m = 0; m < 4; ++m) {
    #pragma unroll
    for (int j = 0; j < 4; ++j) {
      u32 best = umx(umx((u32)(acc[m][0][j] << 8) + Cr0,
                         (u32)(acc[m][1][j] << 8) + (Cr0 - 16u)),
                     umx((u32)(acc[m][2][j] << 8) + (Cr0 - 32u),
                         (u32)(acc[m][3][j] << 8) + (Cr0 - 48u)));
      #pragma unroll
      for (int s = 1; s < 16; s <<= 1)
        best = umx(best, (u32)__shfl_xor((int)best, s, 64));
      if (lcol == 0) {
        u32 col = (u32)tileC + 255u - (best & 255u);
        rowLds[wn * 128 + wm * 64 + m * 16 + lrow * 4 + j] =
            ((u64)(best >> 8) << 32) | (u32)~col;
      }
    }
  }
  // col best: per source col (n,lcol), reduce over (m,j) then lrow (xor 16,32)
  u32 Cc0 = KB + 127u - (u32)(wm * 64 + lrow * 4);
  #pragma unroll
  for (int n = 0; n < 4; ++n) {
    u32 best = 0u;
    #pragma unroll
    for (int m = 0; m < 4; ++m)
      #pragma unroll
      for (int j = 0; j < 4; ++j)
        best = umx(best, (u32)(acc[m][n][j] << 8) + (Cc0 - (u32)(m * 16 + j)));
    best = umx(best, (u32)__shfl_xor((int)best, 16, 64));
    best = umx(best, (u32)__shfl_xor((int)best, 32, 64));
    if (lrow == 0) {
      u32 row = (u32)tileR + 127u - (best & 255u);
      colLds[wm * 256 + wn * 64 + n * 16 + lcol] =
          ((u64)(best >> 8) << 32) | (u32)~row;
    }
  }
  __syncthreads();
  if (tid < 128) {
    u64 b2 = rowLds[tid];
    b2 = umax(b2, rowLds[128 + tid]);
    b2 = umax(b2, rowLds[256 + tid]);
    b2 = umax(b2, rowLds[384 + tid]);
    atomicMax(&rowP[tileR + tid], b2);   // deterministic (exact max)
  } else if (tid < 384) {
    int c = tid - 128;
    atomicMax(&colP[tileC + c], umax(colLds[c], colLds[256 + c]));
  }
#undef KSRUN
#undef MM
}

// analytic loss from rowP/colP (2 loads/thread) -> per-block sums; the LAST
// block (device atomic counter) sums the 36 partials in fixed order.
__global__ __launch_bounds__(256) void k_redloss(const u64* __restrict__ rowP,
                                                 const u64* __restrict__ colP,
                                                 const float* __restrict__ sq_s,
                                                 const float* __restrict__ sq_t,
                                                 float* __restrict__ part,
                                                 u32* __restrict__ ctr,
                                                 float* __restrict__ out) {
  __shared__ float r0[256], r1[256];
  __shared__ int lastFlag;
  int t = threadIdx.x;
  int n = blockIdx.x * 256 + t;   // grid 36 -> 9216
  float lt = 0.f, ls = 0.f;
  if (n < NP) {
    u64 r = rowP[n], c = colP[n];
    {
      float sc = (float)((int)(u32)(r >> 32) - DBIAS) * QS2;
      u32 m = ~((u32)r);
      float a = sq_t[n], cc = sq_s[m];
      lt = a + cc - 2.f * sc * (sqrtf(a) + FEPS) * (sqrtf(cc) + FEPS);
    }
    {
      float sc = (float)((int)(u32)(c >> 32) - DBIAS) * QS2;
      u32 m = ~((u32)c);
      float a = sq_s[n], cc = sq_t[m];
      ls = a + cc - 2.f * sc * (sqrtf(a) + FEPS) * (sqrtf(cc) + FEPS);
    }
  }
  r0[t] = lt; r1[t] = ls;
  __syncthreads();
  for (int s = 128; s > 0; s >>= 1) {
    if (t < s) { r0[t] += r0[t + s]; r1[t] += r1[t + s]; }
    __syncthreads();
  }
  if (t == 0) {
    part[blockIdx.x * 2] = r0[0];
    part[blockIdx.x * 2 + 1] = r1[0];
    __threadfence();
    u32 o = atomicAdd(ctr, 1u);          // device-scope
    lastFlag = (o == 35u) ? 1 : 0;
  }
  __syncthreads();
  if (lastFlag && t < 64) {
    float flt = 0.f, fls = 0.f;
    if (t < 36) {
      flt = __hip_atomic_load(&part[t * 2], __ATOMIC_RELAXED,
                              __HIP_MEMORY_SCOPE_AGENT);
      fls = __hip_atomic_load(&part[t * 2 + 1], __ATOMIC_RELAXED,
                              __HIP_MEMORY_SCOPE_AGENT);
    }
    #pragma unroll
    for (int s = 1; s < 64; s <<= 1) {
      flt += __shfl_xor(flt, s, 64);
      fls += __shfl_xor(fls, s, 64);
    }
    if (t == 0) {
      const float scale = 0.5f / ((float)NP * (float)DD);
      out[0] = flt * scale;   // loss_target
      out[1] = fls * scale;   // loss_source
    }
  }
}

extern "C" void kernel_launch(void* const* d_in, const int* in_sizes, int n_in,
                              void* d_out, int out_size, void* d_ws, size_t ws_size,
                              hipStream_t stream) {
  const float* src = (const float*)d_in[0];
  const float* tgt = (const float*)d_in[1];
  float* out = (float*)d_out;
  char* ws = (char*)d_ws;
  size_t o = 0;
  int8_t* Sq = (int8_t*)(ws + o); o += (size_t)NPAD2 * DD;
  int8_t* Tq = (int8_t*)(ws + o); o += (size_t)NPAD2 * DD;
  float* sq_s = (float*)(ws + o); o += (size_t)NPAD2 * 4;
  float* sq_t = (float*)(ws + o); o += (size_t)NPAD2 * 4;
  float* qpart = (float*)(ws + o); o += (size_t)8 * HH * WW * 4;
  u64* rowP = (u64*)(ws + o); o += (size_t)NPAD2 * 8;
  u64* colP = (u64*)(ws + o); o += (size_t)NPAD2 * 8;
  float* part = (float*)(ws + o); o += 512;
  u32* ctr = (u32*)(ws + o); o += 64;
  if (ws_size < o) return;  // ~19.5 MiB needed

  k_q<<<dim3(36, 4, 2), 256, 0, stream>>>(src, tgt, qpart, Sq, Tq, rowP, colP, ctr);
  k_norm<<<dim3(8, PH, 2), 128, 0, stream>>>(src, tgt, qpart, sq_s, sq_t, Sq, Tq);
  k_gemm<<<NBLK3, 512, 0, stream>>>(Tq, Sq, rowP, colP);
  k_redloss<<<36, 256, 0, stream>>>(rowP, colP, sq_s, sq_t, part, ctr, out);
}

// Round 21
// 129.208 us; speedup vs baseline: 1.3405x; 1.3405x over previous
//
#include <hip/hip_runtime.h>
#include <hip/hip_bf16.h>
#include <stdint.h>

#define HH 96
#define WW 96
#define NCH 256
#define PH 95
#define PW 95
#define NP 9025          // PH*PW
#define DD 1024          // 4*NCH (bytes per row in i8)
#define FEPS 1e-8f

#define BMT 128          // target rows per block
#define BNS 256          // source cols per block
#define NTM 72           // row tiles (9216/128)
#define NTN 36           // col tiles (9216/256)
#define NPAD2 9216
#define NBLK3 2592       // NTM*NTN (divisible by 8)
#define KT 16            // DD/64
#define QSCL 508.0f
#define QS2 (1.0f / (508.0f * 508.0f))
#define DBIAS (1 << 19)  // dot bias (Cauchy-Schwarz: |dot| <= ~274K < 2^19)

typedef __attribute__((ext_vector_type(4))) int i32x4;
typedef __attribute__((ext_vector_type(4))) unsigned int u32x4;
typedef unsigned long long u64;
typedef unsigned int u32;
using bf16 = __hip_bfloat16;

__device__ __forceinline__ u32 umx(u32 a, u32 b) { return a > b ? a : b; }
__device__ __forceinline__ u64 umax(u64 a, u64 b) { return a > b ? a : b; }

// per-pixel partial (64-ch) sum of squares; g=blockIdx.y, img=blockIdx.z.
// Also zeroes pad rows of Sq/Tq (g==0), rowP/colP (g==1), and the counter.
__global__ __launch_bounds__(256) void k_q(const float* __restrict__ src,
                                           const float* __restrict__ tgt,
                                           float* __restrict__ qpart,
                                           int8_t* __restrict__ Sq,
                                           int8_t* __restrict__ Tq,
                                           u64* __restrict__ rowP,
                                           u64* __restrict__ colP,
                                           u32* __restrict__ ctr) {
  int p = blockIdx.x * 256 + threadIdx.x;  // 36*256 == 9216 exactly
  int g = blockIdx.y;                      // channel group (4 x 64)
  const float* img = blockIdx.z ? tgt : src;
  const float* base = img + (size_t)(g * 64) * (HH * WW);
  float acc = 0.f;
  #pragma unroll 8
  for (int c = 0; c < 64; ++c) {
    float v = base[(size_t)c * (HH * WW) + p];
    acc = fmaf(v, v, acc);
  }
  qpart[((size_t)blockIdx.z * 4 + g) * (HH * WW) + p] = acc;
  if (g == 0) {  // zero pad rows NP..NPAD2 (pad dot = 0, never wins)
    const int padWords = (NPAD2 - NP) * DD / 4;  // u32 words
    u32* pw = (u32*)((blockIdx.z ? Tq : Sq) + (size_t)NP * DD);
    for (int j = p; j < padWords; j += 36 * 256) pw[j] = 0u;
  }
  if (g == 1) {  // zero the argmax accumulators (atomicMax targets)
    (blockIdx.z ? colP : rowP)[p] = 0ull;
  }
  if (p == 0 && g == 0 && blockIdx.z == 0) *ctr = 0u;
}

// normalized, globally-scaled i8 patch matrix [NPAD2][DD] via LDS transpose.
// jx-FOLDED (R19): one block loads a full 96-col image row once and emits
// BOTH column shifts -> image reads halved. Per-row sq recomputed in-block
// from qpart; bx==0 blocks store sq. 16 i8 -> one dwordx4 store.
// grid (8 = iy*4+cgroup, PH, z); z = 0: src -> Sq, sq_s ; z = 1: tgt -> Tq.
__global__ __launch_bounds__(128) void k_norm(const float* __restrict__ src,
                                              const float* __restrict__ tgt,
                                              const float* __restrict__ qpart,
                                              float* __restrict__ sq_s,
                                              float* __restrict__ sq_t,
                                              int8_t* __restrict__ Sq,
                                              int8_t* __restrict__ Tq) {
  __shared__ float tile[64 * 97];   // [c][x], odd stride
  __shared__ float rn[PW];
  const float* img = blockIdx.z ? tgt : src;
  int8_t* out = blockIdx.z ? Tq : Sq;
  int bx = blockIdx.x;
  int iy = bx >> 2;                 // row shift
  int c0 = (bx & 3) * 64;           // channel group
  int y = blockIdx.y;
  int t = threadIdx.x;
  if (t < PW) {                     // recompute per-patch squared norm locally
    const float* qp = qpart + (size_t)blockIdx.z * 4 * (HH * WW);
    int b = y * WW + t;
    float s = 0.f;
    #pragma unroll
    for (int g = 0; g < 4; ++g) {
      const float* q = qp + (size_t)g * (HH * WW);
      s += q[b] + q[b + 1] + q[b + WW] + q[b + WW + 1];
    }
    if (bx == 0) (blockIdx.z ? sq_t : sq_s)[y * PW + t] = s;
    rn[t] = QSCL / (sqrtf(s) + FEPS);
  }
  if (t < 96) {                     // load 64 channels x full 96-col row y+iy
    const float* base = img + (size_t)(y + iy) * WW + t;
    #pragma unroll 4
    for (int c = 0; c < 64; ++c)
      tile[c * 97 + t] = base[(size_t)(c0 + c) * (HH * WW)];
  }
  __syncthreads();
  int part = t & 3;                 // 16 d's per part
  int xl0 = t >> 2;                 // 32 xl per pass
  #pragma unroll
  for (int jx = 0; jx < 2; ++jx) {
    int d0 = (iy * 2 + jx) * 256 + c0 + part * 16;
    #pragma unroll
    for (int pass = 0; pass < 3; ++pass) {
      int xl = xl0 + pass * 32;
      if (xl < PW) {
        float r = rn[xl];
        u32x4 w;
        #pragma unroll
        for (int g = 0; g < 4; ++g) {
          u32 pk = 0;
          #pragma unroll
          for (int bb = 0; bb < 4; ++bb) {
            int dl = part * 16 + g * 4 + bb;
            float qv = tile[dl * 97 + xl + jx] * r;
            qv = fminf(fmaxf(qv, -127.f), 127.f);
            pk |= ((u32)(uint8_t)(int8_t)(int)rintf(qv)) << (8 * bb);
          }
          w[g] = pk;
        }
        *(u32x4*)(out + (size_t)(y * PW + xl) * DD + d0) = w;
      }
    }
  }
}

// ---- inline-asm helpers ----
#define DSR(dst, base, IMMSTR) \
  asm volatile("ds_read_b128 %0, %1 offset:" IMMSTR : "=v"(dst) : "v"(base))
#define WAITL(NSTR) asm volatile("s_waitcnt lgkmcnt(" NSTR ")" ::: "memory")
#define SB0 __builtin_amdgcn_sched_barrier(0)

// 128x256-tile i8 MFMA GEMM (dot = Tq . Sq^T exact i32; cos = dot*QS2).
// R11 schedule + R17 L2-aware tile order (FETCH 326->82MB) + R18 atomicMax
// epilogue. LDS: [dbuf 2][A 128x64B | B 256x64B] = 48 KiB; 2 blocks/CU.
// NOTE: 128 regs/wave (64 VGPR + 64 acc) x 16 waves/CU = full register pool;
// (512,6) spills catastrophically (R12). Schedule variants R8/R9/R14/R15 and
// R20's 1-barrier ring (161us + intermittent stalls) all null-or-worse ->
// ~112us is this structure's latency-bound plateau. DO NOT RE-TUNE.
__global__ __launch_bounds__(512, 4) void k_gemm(const int8_t* __restrict__ Tq,
                                                 const int8_t* __restrict__ Sq,
                                                 u64* __restrict__ rowP,
                                                 u64* __restrict__ colP) {
  __shared__ __align__(16) char ldsc[49152];

  int bid = blockIdx.x;
  // L2-aware order: XCD = bid&7 owns rt in [xcd*9, xcd*9+9); within the XCD,
  // 3 ct-stripes of 12, rt-major inside each stripe. Bijective: 8*3*9*12=2592.
  int xcd = bid & 7, loc = bid >> 3;     // loc in [0, 324)
  int stripe = loc / 108;                // 0..2
  int w2 = loc - stripe * 108;           // 0..107
  int rt = xcd * 9 + w2 / 12;
  int ct = stripe * 12 + (w2 % 12);
  int tileR = rt * BMT, tileC = ct * BNS;

  int tid = threadIdx.x;
  int lane = tid & 63, wid = tid >> 6;
  int wm = wid >> 2, wn = wid & 3;       // 2 x 4 wave grid; per-wave out 64x64
  int lcol = lane & 15, lrow = lane >> 4;

  const int8_t* gA = Tq + (size_t)tileR * DD;
  const int8_t* gB = Sq + (size_t)tileC * DD;

  i32x4 acc[4][4] = {};

  // LDS read bases: swizzle term (lrow ^ ((lcol>>1)&3))*16, fragment-invariant
  u32 lbase = (u32)(uintptr_t)ldsc;
  u32 swz16 = ((u32)(lrow ^ ((lcol >> 1) & 3))) << 4;
  u32 aoff0 = lbase + (u32)(wm * 64 + lcol) * 64u + swz16;
  u32 boff0 = lbase + 8192u + (u32)(wn * 64 + lcol) * 64u + swz16;
  u32 aoff1 = aoff0 + 24576u, boff1 = boff0 + 24576u;

  // stage K-tile t into dbuf db: linear LDS dest + inverse-swizzled global col
  auto STAGE = [&](int db, int t) {
    int k0 = t * 64;
    {
      int r = tid >> 2, s = tid & 3;     // A: 128x64B, 1 chunk/thread
      const int8_t* g = gA + (size_t)r * DD + k0 + ((s ^ ((r >> 1) & 3)) << 4);
      __builtin_amdgcn_global_load_lds(
          (const __attribute__((address_space(1))) void*)g,
          (__attribute__((address_space(3))) void*)(ldsc + db * 24576 + tid * 16),
          16, 0, 0);
    }
    #pragma unroll
    for (int q2 = 0; q2 < 2; ++q2) {     // B: 256x64B, 2 chunks/thread
      int ch = q2 * 512 + tid;
      int r = ch >> 2, s = ch & 3;
      const int8_t* g = gB + (size_t)r * DD + k0 + ((s ^ ((r >> 1) & 3)) << 4);
      __builtin_amdgcn_global_load_lds(
          (const __attribute__((address_space(1))) void*)g,
          (__attribute__((address_space(3))) void*)(ldsc + db * 24576 + 8192 + ch * 16),
          16, 0, 0);
    }
  };

  i32x4 a[4], b[4];
#define MM(m) do { \
    acc[m][0] = __builtin_amdgcn_mfma_i32_16x16x64_i8(a[m], b[0], acc[m][0], 0, 0, 0); \
    acc[m][1] = __builtin_amdgcn_mfma_i32_16x16x64_i8(a[m], b[1], acc[m][1], 0, 0, 0); \
    acc[m][2] = __builtin_amdgcn_mfma_i32_16x16x64_i8(a[m], b[2], acc[m][2], 0, 0, 0); \
    acc[m][3] = __builtin_amdgcn_mfma_i32_16x16x64_i8(a[m], b[3], acc[m][3], 0, 0, 0); \
  } while (0)

#define KSRUN(AOFF, BOFF) do { \
    DSR(a[0], AOFF, "0"); \
    DSR(b[0], BOFF, "0");    DSR(b[1], BOFF, "1024"); \
    DSR(b[2], BOFF, "2048"); DSR(b[3], BOFF, "3072"); \
    DSR(a[1], AOFF, "1024"); DSR(a[2], AOFF, "2048"); DSR(a[3], AOFF, "3072"); \
    __builtin_amdgcn_s_setprio(1); \
    WAITL("3"); SB0; MM(0); \
    WAITL("2"); SB0; MM(1); \
    WAITL("1"); SB0; MM(2); \
    WAITL("0"); SB0; MM(3); \
    __builtin_amdgcn_s_setprio(0); \
  } while (0)

  STAGE(0, 0);
  for (int it = 0; it < KT / 2; ++it) {
    int t1 = 2 * it + 1, t2 = 2 * it + 2;
    __builtin_amdgcn_s_barrier();        // reads of tile 2it-1 retired
    STAGE(1, t1);                        // t1 <= 15 always
    asm volatile("s_waitcnt vmcnt(3)" ::: "memory");   // tile 2it landed
    __builtin_amdgcn_s_barrier();        // visible to all waves
    KSRUN(aoff0, boff0);
    __builtin_amdgcn_s_barrier();        // reads of tile 2it retired
    if (t2 < KT) {
      STAGE(0, t2);
      asm volatile("s_waitcnt vmcnt(3)" ::: "memory");
    } else {
      asm volatile("s_waitcnt vmcnt(0)" ::: "memory");
    }
    __builtin_amdgcn_s_barrier();
    KSRUN(aoff1, boff1);
  }

  // ---- epilogue: integer-key argmax -> LDS block-reduce -> atomicMax ----
  __syncthreads();                  // full drain; LDS now reusable
  u64* rowLds = (u64*)ldsc;           // [4 wn][128 rows]  4KB
  u64* colLds = (u64*)(ldsc + 4096);  // [2 wm][256 cols]  4KB

  const u32 KB = ((u32)DBIAS) << 8;   // bias<<8
  // row best: per target row (m,lrow,j), reduce over n then lcol (16 lanes)
  u32 Cr0 = KB + 255u - (u32)(wn * 64 + lcol);
  #pragma unroll
  for (int m = 0; m < 4; ++m) {
    #pragma unroll
    for (int j = 0; j < 4; ++j) {
      u32 best = umx(umx((u32)(acc[m][0][j] << 8) + Cr0,
                         (u32)(acc[m][1][j] << 8) + (Cr0 - 16u)),
                     umx((u32)(acc[m][2][j] << 8) + (Cr0 - 32u),
                         (u32)(acc[m][3][j] << 8) + (Cr0 - 48u)));
      #pragma unroll
      for (int s = 1; s < 16; s <<= 1)
        best = umx(best, (u32)__shfl_xor((int)best, s, 64));
      if (lcol == 0) {
        u32 col = (u32)tileC + 255u - (best & 255u);
        rowLds[wn * 128 + wm * 64 + m * 16 + lrow * 4 + j] =
            ((u64)(best >> 8) << 32) | (u32)~col;
      }
    }
  }
  // col best: per source col (n,lcol), reduce over (m,j) then lrow (xor 16,32)
  u32 Cc0 = KB + 127u - (u32)(wm * 64 + lrow * 4);
  #pragma unroll
  for (int n = 0; n < 4; ++n) {
    u32 best = 0u;
    #pragma unroll
    for (int m = 0; m < 4; ++m)
      #pragma unroll
      for (int j = 0; j < 4; ++j)
        best = umx(best, (u32)(acc[m][n][j] << 8) + (Cc0 - (u32)(m * 16 + j)));
    best = umx(best, (u32)__shfl_xor((int)best, 16, 64));
    best = umx(best, (u32)__shfl_xor((int)best, 32, 64));
    if (lrow == 0) {
      u32 row = (u32)tileR + 127u - (best & 255u);
      colLds[wm * 256 + wn * 64 + n * 16 + lcol] =
          ((u64)(best >> 8) << 32) | (u32)~row;
    }
  }
  __syncthreads();
  if (tid < 128) {
    u64 b2 = rowLds[tid];
    b2 = umax(b2, rowLds[128 + tid]);
    b2 = umax(b2, rowLds[256 + tid]);
    b2 = umax(b2, rowLds[384 + tid]);
    atomicMax(&rowP[tileR + tid], b2);   // deterministic (exact max)
  } else if (tid < 384) {
    int c = tid - 128;
    atomicMax(&colP[tileC + c], umax(colLds[c], colLds[256 + c]));
  }
#undef KSRUN
#undef MM
}

// analytic loss from rowP/colP (2 loads/thread) -> per-block sums; the LAST
// block (device atomic counter) sums the 36 partials in fixed order.
__global__ __launch_bounds__(256) void k_redloss(const u64* __restrict__ rowP,
                                                 const u64* __restrict__ colP,
                                                 const float* __restrict__ sq_s,
                                                 const float* __restrict__ sq_t,
                                                 float* __restrict__ part,
                                                 u32* __restrict__ ctr,
                                                 float* __restrict__ out) {
  __shared__ float r0[256], r1[256];
  __shared__ int lastFlag;
  int t = threadIdx.x;
  int n = blockIdx.x * 256 + t;   // grid 36 -> 9216
  float lt = 0.f, ls = 0.f;
  if (n < NP) {
    u64 r = rowP[n], c = colP[n];
    {
      float sc = (float)((int)(u32)(r >> 32) - DBIAS) * QS2;
      u32 m = ~((u32)r);
      float a = sq_t[n], cc = sq_s[m];
      lt = a + cc - 2.f * sc * (sqrtf(a) + FEPS) * (sqrtf(cc) + FEPS);
    }
    {
      float sc = (float)((int)(u32)(c >> 32) - DBIAS) * QS2;
      u32 m = ~((u32)c);
      float a = sq_s[n], cc = sq_t[m];
      ls = a + cc - 2.f * sc * (sqrtf(a) + FEPS) * (sqrtf(cc) + FEPS);
    }
  }
  r0[t] = lt; r1[t] = ls;
  __syncthreads();
  for (int s = 128; s > 0; s >>= 1) {
    if (t < s) { r0[t] += r0[t + s]; r1[t] += r1[t + s]; }
    __syncthreads();
  }
  if (t == 0) {
    part[blockIdx.x * 2] = r0[0];
    part[blockIdx.x * 2 + 1] = r1[0];
    __threadfence();
    u32 o = atomicAdd(ctr, 1u);          // device-scope
    lastFlag = (o == 35u) ? 1 : 0;
  }
  __syncthreads();
  if (lastFlag && t < 64) {
    float flt = 0.f, fls = 0.f;
    if (t < 36) {
      flt = __hip_atomic_load(&part[t * 2], __ATOMIC_RELAXED,
                              __HIP_MEMORY_SCOPE_AGENT);
      fls = __hip_atomic_load(&part[t * 2 + 1], __ATOMIC_RELAXED,
                              __HIP_MEMORY_SCOPE_AGENT);
    }
    #pragma unroll
    for (int s = 1; s < 64; s <<= 1) {
      flt += __shfl_xor(flt, s, 64);
      fls += __shfl_xor(fls, s, 64);
    }
    if (t == 0) {
      const float scale = 0.5f / ((float)NP * (float)DD);
      out[0] = flt * scale;   // loss_target
      out[1] = fls * scale;   // loss_source
    }
  }
}

extern "C" void kernel_launch(void* const* d_in, const int* in_sizes, int n_in,
                              void* d_out, int out_size, void* d_ws, size_t ws_size,
                              hipStream_t stream) {
  const float* src = (const float*)d_in[0];
  const float* tgt = (const float*)d_in[1];
  float* out = (float*)d_out;
  char* ws = (char*)d_ws;
  size_t o = 0;
  int8_t* Sq = (int8_t*)(ws + o); o += (size_t)NPAD2 * DD;
  int8_t* Tq = (int8_t*)(ws + o); o += (size_t)NPAD2 * DD;
  float* sq_s = (float*)(ws + o); o += (size_t)NPAD2 * 4;
  float* sq_t = (float*)(ws + o); o += (size_t)NPAD2 * 4;
  float* qpart = (float*)(ws + o); o += (size_t)8 * HH * WW * 4;
  u64* rowP = (u64*)(ws + o); o += (size_t)NPAD2 * 8;
  u64* colP = (u64*)(ws + o); o += (size_t)NPAD2 * 8;
  float* part = (float*)(ws + o); o += 512;
  u32* ctr = (u32*)(ws + o); o += 64;
  if (ws_size < o) return;  // ~19.5 MiB needed

  k_q<<<dim3(36, 4, 2), 256, 0, stream>>>(src, tgt, qpart, Sq, Tq, rowP, colP, ctr);
  k_norm<<<dim3(8, PH, 2), 128, 0, stream>>>(src, tgt, qpart, sq_s, sq_t, Sq, Tq);
  k_gemm<<<NBLK3, 512, 0, stream>>>(Tq, Sq, rowP, colP);
  k_redloss<<<36, 256, 0, stream>>>(rowP, colP, sq_s, sq_t, part, ctr, out);
}